// Round 1
// baseline (2401.213 us; speedup 1.0000x reference)
//
#include <hip/hip_runtime.h>
#include <math.h>

#define NN 50000
#define EE 800000
#define EPS 1e-5f

// ---------------------------------------------------------------------------
// CSR build: histogram -> scan -> scatter
// ---------------------------------------------------------------------------
__global__ void hist_kernel(const int* __restrict__ dst, int* cnt) {
    int e = blockIdx.x * blockDim.x + threadIdx.x;
    if (e < EE) atomicAdd(&cnt[dst[e]], 1);
}

// single block, 256 threads; cntcur holds counts on entry, cursors on exit
__global__ void scan_kernel(int* cntcur, int* row_start) {
    __shared__ int part[256];
    int t = threadIdx.x;
    const int CH = (NN + 255) / 256;
    int beg = t * CH;
    int end = beg + CH; if (end > NN) end = NN;
    int s = 0;
    for (int i = beg; i < end; ++i) s += cntcur[i];
    part[t] = s;
    __syncthreads();
    if (t == 0) {
        int run = 0;
        for (int i = 0; i < 256; ++i) { int v = part[i]; part[i] = run; run += v; }
    }
    __syncthreads();
    int run = part[t];
    for (int i = beg; i < end; ++i) {
        int c = cntcur[i];
        row_start[i] = run;
        cntcur[i] = run;   // cursor for scatter
        run += c;
    }
    if (t == 255) row_start[NN] = run;
}

__global__ void scatter_kernel(const int* __restrict__ ei, const float* __restrict__ ea,
                               int* cursor, int* __restrict__ src_sorted,
                               float* __restrict__ ea_sorted) {
    int e = blockIdx.x * blockDim.x + threadIdx.x;
    if (e < EE) {
        int d = ei[EE + e];
        int pos = atomicAdd(&cursor[d], 1);
        src_sorted[pos] = ei[e];
        ea_sorted[pos] = ea[e];
    }
}

// ---------------------------------------------------------------------------
// fp32 GEMM: C[M x (coff..)] = A[M x 128] * B[128 x nc]; 64x64 tile, 4x4 micro
// ---------------------------------------------------------------------------
__global__ __launch_bounds__(256) void gemm_tile(const float* __restrict__ A,
                                                 const float* __restrict__ B,
                                                 float* __restrict__ C,
                                                 int M, int nc, int ldb, int ldc, int coff) {
    __shared__ float As[128][64];  // [k][m]
    __shared__ float Bs[128][64];  // [k][c]
    int t  = threadIdx.x;
    int bm = blockIdx.x * 64;
    int bn = blockIdx.y * 64;

    {   // load A tile, transposed into LDS
        int k4 = (t & 31) << 2;
        int r0 = t >> 5;
#pragma unroll
        for (int pass = 0; pass < 8; ++pass) {
            int row = r0 + pass * 8;
            int gm  = bm + row;
            float4 v = make_float4(0.f, 0.f, 0.f, 0.f);
            if (gm < M) v = *(const float4*)(A + (size_t)gm * 128 + k4);
            As[k4 + 0][row] = v.x; As[k4 + 1][row] = v.y;
            As[k4 + 2][row] = v.z; As[k4 + 3][row] = v.w;
        }
    }
    {   // load B tile
        int c4 = (t & 15) << 2;
        int kr = t >> 4;
#pragma unroll
        for (int pass = 0; pass < 8; ++pass) {
            int k  = kr + pass * 16;
            int gc = bn + c4;
            float4 v = make_float4(0.f, 0.f, 0.f, 0.f);
            if (gc < nc) v = *(const float4*)(B + (size_t)k * ldb + gc);
            *(float4*)&Bs[k][c4] = v;
        }
    }
    __syncthreads();

    int tx = t & 15, ty = t >> 4;
    int m0 = ty * 4, c0 = tx * 4;
    float acc[4][4] = {{0.f}};
#pragma unroll 8
    for (int k = 0; k < 128; ++k) {
        float4 av = *(const float4*)&As[k][m0];
        float4 bv = *(const float4*)&Bs[k][c0];
        float a4[4] = {av.x, av.y, av.z, av.w};
        float b4[4] = {bv.x, bv.y, bv.z, bv.w};
#pragma unroll
        for (int i = 0; i < 4; ++i)
#pragma unroll
            for (int j = 0; j < 4; ++j) acc[i][j] = fmaf(a4[i], b4[j], acc[i][j]);
    }
#pragma unroll
    for (int i = 0; i < 4; ++i) {
        int gm = bm + m0 + i;
        int gc = bn + c0;
        if (gm < M && gc < nc) {
            *(float4*)(C + (size_t)gm * ldc + coff + gc) =
                make_float4(acc[i][0], acc[i][1], acc[i][2], acc[i][3]);
        }
    }
}

// ---------------------------------------------------------------------------
// Node kernel for layers 1-9: one wave per node. HC=128, H=4, C=32.
// xlr: [N][256] = xl | xr. Fuses bias + relu + bn. Writes h[N][128].
// ---------------------------------------------------------------------------
__global__ __launch_bounds__(256) void node_agg_128(const float* __restrict__ xlr,
                                                    const int* __restrict__ row_start,
                                                    const int* __restrict__ src_sorted,
                                                    const float* __restrict__ ea_sorted,
                                                    const float* __restrict__ We,
                                                    const float* __restrict__ att,
                                                    const float* __restrict__ bias,
                                                    const float* __restrict__ bng,
                                                    const float* __restrict__ bnb,
                                                    const float* __restrict__ bnm,
                                                    const float* __restrict__ bnv,
                                                    float* __restrict__ hout) {
    int wave = (blockIdx.x * blockDim.x + threadIdx.x) >> 6;
    int lane = threadIdx.x & 63;
    if (wave >= NN) return;
    int f0 = lane, f1 = lane + 64;

    float xr0 = xlr[(size_t)wave * 256 + 128 + f0];
    float xr1 = xlr[(size_t)wave * 256 + 128 + f1];
    float we0 = We[f0], we1 = We[f1];
    float a0 = att[f0], a1 = att[f1];

    int beg = row_start[wave], end = row_start[wave + 1];
    float mx0 = -INFINITY, mx1 = -INFINITY;
    float sm0 = 0.f, sm1 = 0.f, ac0 = 0.f, ac1 = 0.f;

    for (int j = beg; j < end; ++j) {
        int s = src_sorted[j];
        float eav = ea_sorted[j];
        float xls0 = xlr[(size_t)s * 256 + f0];
        float xls1 = xlr[(size_t)s * 256 + f1];
        float m0 = xls0 + xr0 + eav * we0;
        float m1 = xls1 + xr1 + eav * we1;
        m0 = m0 > 0.f ? m0 : 0.2f * m0;
        m1 = m1 > 0.f ? m1 : 0.2f * m1;
        float p0 = m0 * a0, p1 = m1 * a1;
#pragma unroll
        for (int off = 16; off; off >>= 1) {
            p0 += __shfl_xor(p0, off);
            p1 += __shfl_xor(p1, off);
        }
        float nm0 = fmaxf(mx0, p0);
        float s0  = __expf(mx0 - nm0);
        float w0  = __expf(p0 - nm0);
        sm0 = sm0 * s0 + w0; ac0 = ac0 * s0 + w0 * xls0; mx0 = nm0;

        float nm1 = fmaxf(mx1, p1);
        float s1  = __expf(mx1 - nm1);
        float w1  = __expf(p1 - nm1);
        sm1 = sm1 * s1 + w1; ac1 = ac1 * s1 + w1 * xls1; mx1 = nm1;
    }
    float y0 = ac0 / (sm0 + 1e-16f) + bias[f0];
    float y1 = ac1 / (sm1 + 1e-16f) + bias[f1];
    y0 = fmaxf(y0, 0.f);
    y1 = fmaxf(y1, 0.f);
    y0 = (y0 - bnm[f0]) * rsqrtf(bnv[f0] + EPS) * bng[f0] + bnb[f0];
    y1 = (y1 - bnm[f1]) * rsqrtf(bnv[f1] + EPS) * bng[f1] + bnb[f1];
    hout[(size_t)wave * 128 + f0] = y0;
    hout[(size_t)wave * 128 + f1] = y1;
}

// ---------------------------------------------------------------------------
// Node kernel for layer 10: half-wave per node. H=1, C=32, xlr10: [N][64].
// Fuses bias + relu + bn10 + final linear [32x4] + lin_b. Writes d_out[N][4].
// ---------------------------------------------------------------------------
__global__ __launch_bounds__(256) void node_agg_l10(const float* __restrict__ xlr,
                                                    const int* __restrict__ row_start,
                                                    const int* __restrict__ src_sorted,
                                                    const float* __restrict__ ea_sorted,
                                                    const float* __restrict__ We,
                                                    const float* __restrict__ att,
                                                    const float* __restrict__ bias,
                                                    const float* __restrict__ bng,
                                                    const float* __restrict__ bnb,
                                                    const float* __restrict__ bnm,
                                                    const float* __restrict__ bnv,
                                                    const float* __restrict__ linW,
                                                    const float* __restrict__ linb,
                                                    float* __restrict__ out) {
    int n = (blockIdx.x * blockDim.x + threadIdx.x) >> 5;
    int c = threadIdx.x & 31;
    if (n >= NN) return;

    float xr = xlr[(size_t)n * 64 + 32 + c];
    float we = We[c], a = att[c];
    int beg = row_start[n], end = row_start[n + 1];
    float mx = -INFINITY, sm = 0.f, acc = 0.f;

    for (int j = beg; j < end; ++j) {
        int s = src_sorted[j];
        float eav = ea_sorted[j];
        float xl = xlr[(size_t)s * 64 + c];
        float m = xl + xr + eav * we;
        m = m > 0.f ? m : 0.2f * m;
        float p = m * a;
#pragma unroll
        for (int off = 16; off; off >>= 1) p += __shfl_xor(p, off);
        float nm = fmaxf(mx, p);
        float sc = __expf(mx - nm);
        float w  = __expf(p - nm);
        sm = sm * sc + w; acc = acc * sc + w * xl; mx = nm;
    }
    float y = acc / (sm + 1e-16f) + bias[c];
    y = fmaxf(y, 0.f);
    y = (y - bnm[c]) * rsqrtf(bnv[c] + EPS) * bng[c] + bnb[c];

    float t0 = y * linW[c * 4 + 0];
    float t1 = y * linW[c * 4 + 1];
    float t2 = y * linW[c * 4 + 2];
    float t3 = y * linW[c * 4 + 3];
#pragma unroll
    for (int off = 16; off; off >>= 1) {
        t0 += __shfl_xor(t0, off);
        t1 += __shfl_xor(t1, off);
        t2 += __shfl_xor(t2, off);
        t3 += __shfl_xor(t3, off);
    }
    if (c == 0) {
        out[(size_t)n * 4 + 0] = t0 + linb[0];
        out[(size_t)n * 4 + 1] = t1 + linb[1];
        out[(size_t)n * 4 + 2] = t2 + linb[2];
        out[(size_t)n * 4 + 3] = t3 + linb[3];
    }
}

// ---------------------------------------------------------------------------
extern "C" void kernel_launch(void* const* d_in, const int* in_sizes, int n_in,
                              void* d_out, int out_size, void* d_ws, size_t ws_size,
                              hipStream_t stream) {
    const float* x      = (const float*)d_in[0];
    const int*   ei     = (const int*)d_in[1];
    const float* ea     = (const float*)d_in[2];
    const float* l1_Wl  = (const float*)d_in[3];
    const float* l1_Wr  = (const float*)d_in[4];
    const float* l1_We  = (const float*)d_in[5];
    const float* l1_att = (const float*)d_in[6];
    const float* l1_b   = (const float*)d_in[7];
    const float* mid_Wl = (const float*)d_in[8];
    const float* mid_Wr = (const float*)d_in[9];
    const float* mid_We = (const float*)d_in[10];
    const float* mid_att= (const float*)d_in[11];
    const float* mid_b  = (const float*)d_in[12];
    const float* l10_Wl = (const float*)d_in[13];
    const float* l10_Wr = (const float*)d_in[14];
    const float* l10_We = (const float*)d_in[15];
    const float* l10_att= (const float*)d_in[16];
    const float* l10_b  = (const float*)d_in[17];
    const float* bn_g   = (const float*)d_in[18];
    const float* bn_b   = (const float*)d_in[19];
    const float* bn_m   = (const float*)d_in[20];
    const float* bn_v   = (const float*)d_in[21];
    const float* bn10_g = (const float*)d_in[22];
    const float* bn10_b = (const float*)d_in[23];
    const float* bn10_m = (const float*)d_in[24];
    const float* bn10_v = (const float*)d_in[25];
    const float* lin_W  = (const float*)d_in[26];
    const float* lin_b  = (const float*)d_in[27];

    char* ws = (char*)d_ws;
    auto take = [&](size_t bytes) { char* p = ws; ws += (bytes + 255) & ~size_t(255); return p; };
    int*   row_start  = (int*)  take(sizeof(int) * (NN + 1));
    int*   cursor     = (int*)  take(sizeof(int) * NN);
    int*   src_sorted = (int*)  take(sizeof(int) * EE);
    float* ea_sorted  = (float*)take(sizeof(float) * EE);
    float* xlr        = (float*)take(sizeof(float) * (size_t)NN * 256);
    float* h0         = (float*)take(sizeof(float) * (size_t)NN * 128);
    float* h1         = (float*)take(sizeof(float) * (size_t)NN * 128);

    // --- CSR build ---
    hipMemsetAsync(cursor, 0, sizeof(int) * NN, stream);
    hist_kernel<<<EE / 256, 256, 0, stream>>>(ei + EE, cursor);
    scan_kernel<<<1, 256, 0, stream>>>(cursor, row_start);
    scatter_kernel<<<EE / 256, 256, 0, stream>>>(ei, ea, cursor, src_sorted, ea_sorted);

    const int MB = (NN + 63) / 64;  // 782
    dim3 gg(MB, 2), g1(MB, 1);

    // --- layer 1 ---
    gemm_tile<<<gg, 256, 0, stream>>>(x, l1_Wl, xlr, NN, 128, 128, 256, 0);
    gemm_tile<<<gg, 256, 0, stream>>>(x, l1_Wr, xlr, NN, 128, 128, 256, 128);
    node_agg_128<<<(NN * 64) / 256, 256, 0, stream>>>(
        xlr, row_start, src_sorted, ea_sorted, l1_We, l1_att, l1_b,
        bn_g, bn_b, bn_m, bn_v, h0);

    // --- layers 2-9 ---
    float* hin = h0;
    float* hout = h1;
    for (int i = 0; i < 8; ++i) {
        gemm_tile<<<gg, 256, 0, stream>>>(hin, mid_Wl + (size_t)i * 128 * 128, xlr, NN, 128, 128, 256, 0);
        gemm_tile<<<gg, 256, 0, stream>>>(hin, mid_Wr + (size_t)i * 128 * 128, xlr, NN, 128, 128, 256, 128);
        node_agg_128<<<(NN * 64) / 256, 256, 0, stream>>>(
            xlr, row_start, src_sorted, ea_sorted,
            mid_We + (size_t)i * 128, mid_att + (size_t)i * 128, mid_b + (size_t)i * 128,
            bn_g + (size_t)(i + 1) * 128, bn_b + (size_t)(i + 1) * 128,
            bn_m + (size_t)(i + 1) * 128, bn_v + (size_t)(i + 1) * 128, hout);
        float* tmp = hin; hin = hout; hout = tmp;
    }

    // --- layer 10 (reuses xlr buffer as [N][64]) ---
    gemm_tile<<<g1, 256, 0, stream>>>(hin, l10_Wl, xlr, NN, 32, 32, 64, 0);
    gemm_tile<<<g1, 256, 0, stream>>>(hin, l10_Wr, xlr, NN, 32, 32, 64, 32);
    node_agg_l10<<<(NN * 32 + 255) / 256, 256, 0, stream>>>(
        xlr, row_start, src_sorted, ea_sorted, l10_We, l10_att, l10_b,
        bn10_g, bn10_b, bn10_m, bn10_v, lin_W, lin_b, (float*)d_out);
}

// Round 2
// 1630.834 us; speedup vs baseline: 1.4724x; 1.4724x over previous
//
#include <hip/hip_runtime.h>
#include <math.h>

#define NN 50000
#define EE 800000
#define EPS 1e-5f

// ---------------------------------------------------------------------------
// CSR build: histogram -> scan -> scatter
// ---------------------------------------------------------------------------
__global__ void hist_kernel(const int* __restrict__ dst, int* cnt) {
    int e = blockIdx.x * blockDim.x + threadIdx.x;
    if (e < EE) atomicAdd(&cnt[dst[e]], 1);
}

__global__ void scan_kernel(int* cntcur, int* row_start) {
    __shared__ int part[256];
    int t = threadIdx.x;
    const int CH = (NN + 255) / 256;
    int beg = t * CH;
    int end = beg + CH; if (end > NN) end = NN;
    int s = 0;
    for (int i = beg; i < end; ++i) s += cntcur[i];
    part[t] = s;
    __syncthreads();
    if (t == 0) {
        int run = 0;
        for (int i = 0; i < 256; ++i) { int v = part[i]; part[i] = run; run += v; }
    }
    __syncthreads();
    int run = part[t];
    for (int i = beg; i < end; ++i) {
        int c = cntcur[i];
        row_start[i] = run;
        cntcur[i] = run;
        run += c;
    }
    if (t == 255) row_start[NN] = run;
}

__global__ void scatter_kernel(const int* __restrict__ ei, const float* __restrict__ ea,
                               int* cursor, int* __restrict__ src_sorted,
                               float* __restrict__ ea_sorted) {
    int e = blockIdx.x * blockDim.x + threadIdx.x;
    if (e < EE) {
        int d = ei[EE + e];
        int pos = atomicAdd(&cursor[d], 1);
        src_sorted[pos] = ei[e];
        ea_sorted[pos] = ea[e];
    }
}

// ---------------------------------------------------------------------------
// Fused dual GEMM: C[M x 256] = A[M x 128] @ [Wl | Wr] (each 128x128).
// 128x128 tile per block, 8x8 microtile, K-tile 32 (33 KB LDS -> 4 blocks/CU).
// blockIdx.y selects Wl (cols 0-127) or Wr (cols 128-255).
// ---------------------------------------------------------------------------
#define LDP 132   // LDS row pad: multiple of 4 floats keeps b128 alignment
__global__ __launch_bounds__(256) void gemm_dual(const float* __restrict__ A,
                                                 const float* __restrict__ Wl,
                                                 const float* __restrict__ Wr,
                                                 float* __restrict__ C, int M) {
    __shared__ float As[32][LDP];   // [k][m] (transposed)
    __shared__ float Bs[32][LDP];   // [k][c]
    const float* B = blockIdx.y ? Wr : Wl;
    int coff = blockIdx.y << 7;
    int t  = threadIdx.x;
    int bm = blockIdx.x * 128;
    int tx = t & 15, ty = t >> 4;

    float acc[8][8];
#pragma unroll
    for (int i = 0; i < 8; ++i)
#pragma unroll
        for (int j = 0; j < 8; ++j) acc[i][j] = 0.f;

    for (int kt = 0; kt < 4; ++kt) {
        int k0 = kt * 32;
        {   // A tile: 128 rows x 32 k, transposed into As[k][m]
            int kk  = (t & 7) * 4;
            int row = t >> 3;
#pragma unroll
            for (int pass = 0; pass < 4; ++pass) {
                int r  = row + pass * 32;
                int gm = bm + r;
                float4 v = make_float4(0.f, 0.f, 0.f, 0.f);
                if (gm < M) v = *(const float4*)(A + (size_t)gm * 128 + k0 + kk);
                As[kk + 0][r] = v.x; As[kk + 1][r] = v.y;
                As[kk + 2][r] = v.z; As[kk + 3][r] = v.w;
            }
            // B tile: 32 k-rows x 128 cols
            int cc = (t & 31) * 4;
            int kr = t >> 5;
#pragma unroll
            for (int pass = 0; pass < 4; ++pass) {
                int k = kr + pass * 8;
                *(float4*)&Bs[k][cc] = *(const float4*)(B + (size_t)(k0 + k) * 128 + cc);
            }
        }
        __syncthreads();
#pragma unroll
        for (int k = 0; k < 32; ++k) {
            float4 A0 = *(const float4*)&As[k][ty * 4];
            float4 A1 = *(const float4*)&As[k][64 + ty * 4];
            float4 B0 = *(const float4*)&Bs[k][tx * 4];
            float4 B1 = *(const float4*)&Bs[k][64 + tx * 4];
            float av[8] = {A0.x, A0.y, A0.z, A0.w, A1.x, A1.y, A1.z, A1.w};
            float bv[8] = {B0.x, B0.y, B0.z, B0.w, B1.x, B1.y, B1.z, B1.w};
#pragma unroll
            for (int i = 0; i < 8; ++i)
#pragma unroll
                for (int j = 0; j < 8; ++j)
                    acc[i][j] = fmaf(av[i], bv[j], acc[i][j]);
        }
        __syncthreads();
    }

#pragma unroll
    for (int i = 0; i < 8; ++i) {
        int r = bm + ((i < 4) ? (ty * 4 + i) : (64 + ty * 4 + i - 4));
        if (r < M) {
            float* crow = C + (size_t)r * 256 + coff;
            *(float4*)(crow + tx * 4)      = make_float4(acc[i][0], acc[i][1], acc[i][2], acc[i][3]);
            *(float4*)(crow + 64 + tx * 4) = make_float4(acc[i][4], acc[i][5], acc[i][6], acc[i][7]);
        }
    }
}

// ---------------------------------------------------------------------------
// Small fp32 GEMM kept for layer 10 (K=128 hardcoded in A stride, nc<=64)
// ---------------------------------------------------------------------------
__global__ __launch_bounds__(256) void gemm_tile(const float* __restrict__ A,
                                                 const float* __restrict__ B,
                                                 float* __restrict__ C,
                                                 int M, int nc, int ldb, int ldc, int coff) {
    __shared__ float As[128][64];
    __shared__ float Bs[128][64];
    int t  = threadIdx.x;
    int bm = blockIdx.x * 64;
    int bn = blockIdx.y * 64;
    {
        int k4 = (t & 31) << 2;
        int r0 = t >> 5;
#pragma unroll
        for (int pass = 0; pass < 8; ++pass) {
            int row = r0 + pass * 8;
            int gm  = bm + row;
            float4 v = make_float4(0.f, 0.f, 0.f, 0.f);
            if (gm < M) v = *(const float4*)(A + (size_t)gm * 128 + k4);
            As[k4 + 0][row] = v.x; As[k4 + 1][row] = v.y;
            As[k4 + 2][row] = v.z; As[k4 + 3][row] = v.w;
        }
    }
    {
        int c4 = (t & 15) << 2;
        int kr = t >> 4;
#pragma unroll
        for (int pass = 0; pass < 8; ++pass) {
            int k  = kr + pass * 16;
            int gc = bn + c4;
            float4 v = make_float4(0.f, 0.f, 0.f, 0.f);
            if (gc < nc) v = *(const float4*)(B + (size_t)k * ldb + gc);
            *(float4*)&Bs[k][c4] = v;
        }
    }
    __syncthreads();

    int tx = t & 15, ty = t >> 4;
    int m0 = ty * 4, c0 = tx * 4;
    float acc[4][4] = {{0.f}};
#pragma unroll 8
    for (int k = 0; k < 128; ++k) {
        float4 av = *(const float4*)&As[k][m0];
        float4 bv = *(const float4*)&Bs[k][c0];
        float a4[4] = {av.x, av.y, av.z, av.w};
        float b4[4] = {bv.x, bv.y, bv.z, bv.w};
#pragma unroll
        for (int i = 0; i < 4; ++i)
#pragma unroll
            for (int j = 0; j < 4; ++j) acc[i][j] = fmaf(a4[i], b4[j], acc[i][j]);
    }
#pragma unroll
    for (int i = 0; i < 4; ++i) {
        int gm = bm + m0 + i;
        int gc = bn + c0;
        if (gm < M && gc < nc) {
            *(float4*)(C + (size_t)gm * ldc + coff + gc) =
                make_float4(acc[i][0], acc[i][1], acc[i][2], acc[i][3]);
        }
    }
}

// ---------------------------------------------------------------------------
// Node kernel layers 1-9: one wave per node. Same-head lane packing:
// lane l -> head h=l>>4, q=l&15; features f0=h*32+q, f1=f0+16.
// Butterfly over 16 lanes only; one softmax state; exp2 domain.
// ---------------------------------------------------------------------------
__global__ __launch_bounds__(256) void node_agg_128(const float* __restrict__ xlr,
                                                    const int* __restrict__ row_start,
                                                    const int* __restrict__ src_sorted,
                                                    const float* __restrict__ ea_sorted,
                                                    const float* __restrict__ We,
                                                    const float* __restrict__ att,
                                                    const float* __restrict__ bias,
                                                    const float* __restrict__ bng,
                                                    const float* __restrict__ bnb,
                                                    const float* __restrict__ bnm,
                                                    const float* __restrict__ bnv,
                                                    float* __restrict__ hout) {
    int wave = (blockIdx.x * blockDim.x + threadIdx.x) >> 6;
    int lane = threadIdx.x & 63;
    if (wave >= NN) return;
    int hh = lane >> 4, q = lane & 15;
    int f0 = hh * 32 + q;          // f1 = f0 + 16

    const float L2E = 1.44269504f;
    const float* xrrow = xlr + (size_t)wave * 256 + 128;
    float xr0 = xrrow[f0], xr1 = xrrow[f0 + 16];
    float we0 = We[f0],    we1 = We[f0 + 16];
    float at0 = att[f0],   at1 = att[f0 + 16];
    float a6_0 = 0.6f * L2E * at0, a4_0 = 0.4f * L2E * at0;
    float a6_1 = 0.6f * L2E * at1, a4_1 = 0.4f * L2E * at1;

    int beg = row_start[wave], end = row_start[wave + 1];
    float mx = -INFINITY, sm = 0.f, ac0 = 0.f, ac1 = 0.f;

    int j = beg;
    for (; j + 1 < end; j += 2) {
        int s0 = src_sorted[j], s1 = src_sorted[j + 1];
        float e0 = ea_sorted[j], e1 = ea_sorted[j + 1];
        const float* r0 = xlr + ((size_t)s0 << 8);
        const float* r1 = xlr + ((size_t)s1 << 8);
        float x00 = r0[f0], x01 = r0[f0 + 16];
        float x10 = r1[f0], x11 = r1[f0 + 16];

        // edge 0
        {
            float m0 = x00 + fmaf(e0, we0, xr0);
            float m1 = x01 + fmaf(e0, we1, xr1);
            float p = fmaf(a6_0, m0, fmaf(a4_0, fabsf(m0),
                      fmaf(a6_1, m1, a4_1 * fabsf(m1))));
            p += __shfl_xor(p, 8); p += __shfl_xor(p, 4);
            p += __shfl_xor(p, 2); p += __shfl_xor(p, 1);
            float nm = fmaxf(mx, p);
            float sc = exp2f(mx - nm);
            float w  = exp2f(p - nm);
            sm  = fmaf(sm, sc, w);
            ac0 = fmaf(ac0, sc, w * x00);
            ac1 = fmaf(ac1, sc, w * x01);
            mx = nm;
        }
        // edge 1
        {
            float m0 = x10 + fmaf(e1, we0, xr0);
            float m1 = x11 + fmaf(e1, we1, xr1);
            float p = fmaf(a6_0, m0, fmaf(a4_0, fabsf(m0),
                      fmaf(a6_1, m1, a4_1 * fabsf(m1))));
            p += __shfl_xor(p, 8); p += __shfl_xor(p, 4);
            p += __shfl_xor(p, 2); p += __shfl_xor(p, 1);
            float nm = fmaxf(mx, p);
            float sc = exp2f(mx - nm);
            float w  = exp2f(p - nm);
            sm  = fmaf(sm, sc, w);
            ac0 = fmaf(ac0, sc, w * x10);
            ac1 = fmaf(ac1, sc, w * x11);
            mx = nm;
        }
    }
    if (j < end) {
        int s0 = src_sorted[j];
        float e0 = ea_sorted[j];
        const float* r0 = xlr + ((size_t)s0 << 8);
        float x00 = r0[f0], x01 = r0[f0 + 16];
        float m0 = x00 + fmaf(e0, we0, xr0);
        float m1 = x01 + fmaf(e0, we1, xr1);
        float p = fmaf(a6_0, m0, fmaf(a4_0, fabsf(m0),
                  fmaf(a6_1, m1, a4_1 * fabsf(m1))));
        p += __shfl_xor(p, 8); p += __shfl_xor(p, 4);
        p += __shfl_xor(p, 2); p += __shfl_xor(p, 1);
        float nm = fmaxf(mx, p);
        float sc = exp2f(mx - nm);
        float w  = exp2f(p - nm);
        sm  = fmaf(sm, sc, w);
        ac0 = fmaf(ac0, sc, w * x00);
        ac1 = fmaf(ac1, sc, w * x01);
        mx = nm;
    }

    float inv = 1.f / (sm + 1e-16f);
    float y0 = fmaf(ac0, inv, bias[f0]);
    float y1 = fmaf(ac1, inv, bias[f0 + 16]);
    y0 = fmaxf(y0, 0.f);
    y1 = fmaxf(y1, 0.f);
    y0 = (y0 - bnm[f0])      * rsqrtf(bnv[f0] + EPS)      * bng[f0]      + bnb[f0];
    y1 = (y1 - bnm[f0 + 16]) * rsqrtf(bnv[f0 + 16] + EPS) * bng[f0 + 16] + bnb[f0 + 16];
    hout[(size_t)wave * 128 + f0]      = y0;
    hout[(size_t)wave * 128 + f0 + 16] = y1;
}

// ---------------------------------------------------------------------------
// Layer 10: half-wave per node. H=1, C=32, xlr10: [N][64].
// ---------------------------------------------------------------------------
__global__ __launch_bounds__(256) void node_agg_l10(const float* __restrict__ xlr,
                                                    const int* __restrict__ row_start,
                                                    const int* __restrict__ src_sorted,
                                                    const float* __restrict__ ea_sorted,
                                                    const float* __restrict__ We,
                                                    const float* __restrict__ att,
                                                    const float* __restrict__ bias,
                                                    const float* __restrict__ bng,
                                                    const float* __restrict__ bnb,
                                                    const float* __restrict__ bnm,
                                                    const float* __restrict__ bnv,
                                                    const float* __restrict__ linW,
                                                    const float* __restrict__ linb,
                                                    float* __restrict__ out) {
    int n = (blockIdx.x * blockDim.x + threadIdx.x) >> 5;
    int c = threadIdx.x & 31;
    if (n >= NN) return;

    const float L2E = 1.44269504f;
    float xr = xlr[(size_t)n * 64 + 32 + c];
    float we = We[c];
    float a6 = 0.6f * L2E * att[c], a4 = 0.4f * L2E * att[c];
    int beg = row_start[n], end = row_start[n + 1];
    float mx = -INFINITY, sm = 0.f, acc = 0.f;

    for (int j = beg; j < end; ++j) {
        int s = src_sorted[j];
        float eav = ea_sorted[j];
        float xl = xlr[(size_t)s * 64 + c];
        float m = xl + fmaf(eav, we, xr);
        float p = fmaf(a6, m, a4 * fabsf(m));
#pragma unroll
        for (int off = 16; off; off >>= 1) p += __shfl_xor(p, off);
        float nm = fmaxf(mx, p);
        float sc = exp2f(mx - nm);
        float w  = exp2f(p - nm);
        sm = fmaf(sm, sc, w);
        acc = fmaf(acc, sc, w * xl);
        mx = nm;
    }
    float y = acc / (sm + 1e-16f) + bias[c];
    y = fmaxf(y, 0.f);
    y = (y - bnm[c]) * rsqrtf(bnv[c] + EPS) * bng[c] + bnb[c];

    float t0 = y * linW[c * 4 + 0];
    float t1 = y * linW[c * 4 + 1];
    float t2 = y * linW[c * 4 + 2];
    float t3 = y * linW[c * 4 + 3];
#pragma unroll
    for (int off = 16; off; off >>= 1) {
        t0 += __shfl_xor(t0, off);
        t1 += __shfl_xor(t1, off);
        t2 += __shfl_xor(t2, off);
        t3 += __shfl_xor(t3, off);
    }
    if (c == 0) {
        out[(size_t)n * 4 + 0] = t0 + linb[0];
        out[(size_t)n * 4 + 1] = t1 + linb[1];
        out[(size_t)n * 4 + 2] = t2 + linb[2];
        out[(size_t)n * 4 + 3] = t3 + linb[3];
    }
}

// ---------------------------------------------------------------------------
extern "C" void kernel_launch(void* const* d_in, const int* in_sizes, int n_in,
                              void* d_out, int out_size, void* d_ws, size_t ws_size,
                              hipStream_t stream) {
    const float* x      = (const float*)d_in[0];
    const int*   ei     = (const int*)d_in[1];
    const float* ea     = (const float*)d_in[2];
    const float* l1_Wl  = (const float*)d_in[3];
    const float* l1_Wr  = (const float*)d_in[4];
    const float* l1_We  = (const float*)d_in[5];
    const float* l1_att = (const float*)d_in[6];
    const float* l1_b   = (const float*)d_in[7];
    const float* mid_Wl = (const float*)d_in[8];
    const float* mid_Wr = (const float*)d_in[9];
    const float* mid_We = (const float*)d_in[10];
    const float* mid_att= (const float*)d_in[11];
    const float* mid_b  = (const float*)d_in[12];
    const float* l10_Wl = (const float*)d_in[13];
    const float* l10_Wr = (const float*)d_in[14];
    const float* l10_We = (const float*)d_in[15];
    const float* l10_att= (const float*)d_in[16];
    const float* l10_b  = (const float*)d_in[17];
    const float* bn_g   = (const float*)d_in[18];
    const float* bn_b   = (const float*)d_in[19];
    const float* bn_m   = (const float*)d_in[20];
    const float* bn_v   = (const float*)d_in[21];
    const float* bn10_g = (const float*)d_in[22];
    const float* bn10_b = (const float*)d_in[23];
    const float* bn10_m = (const float*)d_in[24];
    const float* bn10_v = (const float*)d_in[25];
    const float* lin_W  = (const float*)d_in[26];
    const float* lin_b  = (const float*)d_in[27];

    char* ws = (char*)d_ws;
    auto take = [&](size_t bytes) { char* p = ws; ws += (bytes + 255) & ~size_t(255); return p; };
    int*   row_start  = (int*)  take(sizeof(int) * (NN + 1));
    int*   cursor     = (int*)  take(sizeof(int) * NN);
    int*   src_sorted = (int*)  take(sizeof(int) * EE);
    float* ea_sorted  = (float*)take(sizeof(float) * EE);
    float* xlr        = (float*)take(sizeof(float) * (size_t)NN * 256);
    float* h0         = (float*)take(sizeof(float) * (size_t)NN * 128);
    float* h1         = (float*)take(sizeof(float) * (size_t)NN * 128);

    // --- CSR build ---
    hipMemsetAsync(cursor, 0, sizeof(int) * NN, stream);
    hist_kernel<<<EE / 256, 256, 0, stream>>>(ei + EE, cursor);
    scan_kernel<<<1, 256, 0, stream>>>(cursor, row_start);
    scatter_kernel<<<EE / 256, 256, 0, stream>>>(ei, ea, cursor, src_sorted, ea_sorted);

    const int GB = (NN + 127) / 128;  // 391
    dim3 gdual(GB, 2);

    // --- layer 1 ---
    gemm_dual<<<gdual, 256, 0, stream>>>(x, l1_Wl, l1_Wr, xlr, NN);
    node_agg_128<<<(NN * 64) / 256, 256, 0, stream>>>(
        xlr, row_start, src_sorted, ea_sorted, l1_We, l1_att, l1_b,
        bn_g, bn_b, bn_m, bn_v, h0);

    // --- layers 2-9 ---
    float* hin = h0;
    float* hout = h1;
    for (int i = 0; i < 8; ++i) {
        gemm_dual<<<gdual, 256, 0, stream>>>(hin, mid_Wl + (size_t)i * 128 * 128,
                                             mid_Wr + (size_t)i * 128 * 128, xlr, NN);
        node_agg_128<<<(NN * 64) / 256, 256, 0, stream>>>(
            xlr, row_start, src_sorted, ea_sorted,
            mid_We + (size_t)i * 128, mid_att + (size_t)i * 128, mid_b + (size_t)i * 128,
            bn_g + (size_t)(i + 1) * 128, bn_b + (size_t)(i + 1) * 128,
            bn_m + (size_t)(i + 1) * 128, bn_v + (size_t)(i + 1) * 128, hout);
        float* tmp = hin; hin = hout; hout = tmp;
    }

    // --- layer 10 (xlr reused as [N][64]) ---
    const int MB = (NN + 63) / 64;  // 782
    dim3 g1(MB, 1);
    gemm_tile<<<g1, 256, 0, stream>>>(hin, l10_Wl, xlr, NN, 32, 32, 64, 0);
    gemm_tile<<<g1, 256, 0, stream>>>(hin, l10_Wr, xlr, NN, 32, 32, 64, 32);
    node_agg_l10<<<(NN * 32 + 255) / 256, 256, 0, stream>>>(
        xlr, row_start, src_sorted, ea_sorted, l10_We, l10_att, l10_b,
        bn10_g, bn10_b, bn10_m, bn10_v, lin_W, lin_b, (float*)d_out);
}

// Round 3
// 1626.557 us; speedup vs baseline: 1.4763x; 1.0026x over previous
//
#include <hip/hip_runtime.h>
#include <math.h>

#define NN 50000
#define EE 800000
#define EPS 1e-5f
#define SCAN_CH 196   // ceil(NN/256)

// ---------------------------------------------------------------------------
// CSR build: histogram -> 3-kernel parallel scan -> scatter (packs src+ea)
// ---------------------------------------------------------------------------
__global__ void hist_kernel(const int* __restrict__ dst, int* cnt) {
    int e = blockIdx.x * blockDim.x + threadIdx.x;
    if (e < EE) atomicAdd(&cnt[dst[e]], 1);
}

// 256 blocks x 256 thr: block b reduces cnt[b*196 .. b*196+195] -> part[b]
__global__ void scan_part(const int* __restrict__ cnt, int* __restrict__ part) {
    __shared__ int red[256];
    int b = blockIdx.x, t = threadIdx.x;
    int i = b * SCAN_CH + t;
    int v = (t < SCAN_CH && i < NN) ? cnt[i] : 0;
    red[t] = v;
    __syncthreads();
#pragma unroll
    for (int s = 128; s; s >>= 1) {
        if (t < s) red[t] += red[t + s];
        __syncthreads();
    }
    if (t == 0) part[b] = red[0];
}

// 1 block: exclusive scan of 256 partials
__global__ void scan_block(int* part) {
    __shared__ int buf[2][256];
    int t = threadIdx.x;
    int v = part[t];
    int p = 0;
    buf[0][t] = v;
    __syncthreads();
#pragma unroll
    for (int off = 1; off < 256; off <<= 1) {
        buf[p ^ 1][t] = buf[p][t] + ((t >= off) ? buf[p][t - off] : 0);
        __syncthreads();
        p ^= 1;
    }
    part[t] = buf[p][t] - v;
}

// 256 blocks: in-block inclusive scan + block offset -> row_start & cursor
__global__ void scan_final(int* __restrict__ cntcur, const int* __restrict__ part,
                           int* __restrict__ row_start) {
    __shared__ int buf[2][256];
    int b = blockIdx.x, t = threadIdx.x;
    int i = b * SCAN_CH + t;
    int v = (t < SCAN_CH && i < NN) ? cntcur[i] : 0;
    int p = 0;
    buf[0][t] = v;
    __syncthreads();
#pragma unroll
    for (int off = 1; off < 256; off <<= 1) {
        buf[p ^ 1][t] = buf[p][t] + ((t >= off) ? buf[p][t - off] : 0);
        __syncthreads();
        p ^= 1;
    }
    if (t < SCAN_CH && i < NN) {
        int pos = part[b] + buf[p][t] - v;   // exclusive
        row_start[i] = pos;
        cntcur[i] = pos;                     // scatter cursor
    }
    if (b == 0 && t == 0) row_start[NN] = EE;
}

__global__ void scatter_kernel(const int* __restrict__ ei, const float* __restrict__ ea,
                               int* cursor, int2* __restrict__ edge_pack) {
    int e = blockIdx.x * blockDim.x + threadIdx.x;
    if (e < EE) {
        int d = ei[EE + e];
        int pos = atomicAdd(&cursor[d], 1);
        edge_pack[pos] = make_int2(ei[e], __float_as_int(ea[e]));
    }
}

// ---------------------------------------------------------------------------
// Fused dual GEMM with register prefetch of next K-tile.
// C[M x 256] = A[M x 128] @ [Wl | Wr]; 128x128 tile, 8x8 micro, K-tile 32.
// ---------------------------------------------------------------------------
#define LDP 132
__global__ __launch_bounds__(256) void gemm_dual(const float* __restrict__ A,
                                                 const float* __restrict__ Wl,
                                                 const float* __restrict__ Wr,
                                                 float* __restrict__ C, int M) {
    __shared__ float As[32][LDP];
    __shared__ float Bs[32][LDP];
    const float* B = blockIdx.y ? Wr : Wl;
    int coff = blockIdx.y << 7;
    int t  = threadIdx.x;
    int bm = blockIdx.x * 128;
    int tx = t & 15, ty = t >> 4;

    int kk  = (t & 7) * 4;   // A-load: k within tile
    int row = t >> 3;        // A-load: base row
    int cc  = (t & 31) * 4;  // B-load: col
    int kr  = t >> 5;        // B-load: base k

    float acc[8][8];
#pragma unroll
    for (int i = 0; i < 8; ++i)
#pragma unroll
        for (int j = 0; j < 8; ++j) acc[i][j] = 0.f;

    float4 pa[4], pb[4];
#pragma unroll
    for (int p = 0; p < 4; ++p) {
        int gm = bm + row + p * 32;
        pa[p] = (gm < M) ? *(const float4*)(A + (size_t)gm * 128 + kk)
                         : make_float4(0.f, 0.f, 0.f, 0.f);
        pb[p] = *(const float4*)(B + (size_t)(kr + p * 8) * 128 + cc);
    }

    for (int kt = 0; kt < 4; ++kt) {
#pragma unroll
        for (int p = 0; p < 4; ++p) {
            int r = row + p * 32;
            As[kk + 0][r] = pa[p].x; As[kk + 1][r] = pa[p].y;
            As[kk + 2][r] = pa[p].z; As[kk + 3][r] = pa[p].w;
            *(float4*)&Bs[kr + p * 8][cc] = pb[p];
        }
        __syncthreads();
        if (kt < 3) {
            int k0 = (kt + 1) * 32;
#pragma unroll
            for (int p = 0; p < 4; ++p) {
                int gm = bm + row + p * 32;
                pa[p] = (gm < M) ? *(const float4*)(A + (size_t)gm * 128 + k0 + kk)
                                 : make_float4(0.f, 0.f, 0.f, 0.f);
                pb[p] = *(const float4*)(B + (size_t)(k0 + kr + p * 8) * 128 + cc);
            }
        }
#pragma unroll
        for (int k = 0; k < 32; ++k) {
            float4 A0 = *(const float4*)&As[k][ty * 4];
            float4 A1 = *(const float4*)&As[k][64 + ty * 4];
            float4 B0 = *(const float4*)&Bs[k][tx * 4];
            float4 B1 = *(const float4*)&Bs[k][64 + tx * 4];
            float av[8] = {A0.x, A0.y, A0.z, A0.w, A1.x, A1.y, A1.z, A1.w};
            float bv[8] = {B0.x, B0.y, B0.z, B0.w, B1.x, B1.y, B1.z, B1.w};
#pragma unroll
            for (int i = 0; i < 8; ++i)
#pragma unroll
                for (int j = 0; j < 8; ++j)
                    acc[i][j] = fmaf(av[i], bv[j], acc[i][j]);
        }
        __syncthreads();
    }

#pragma unroll
    for (int i = 0; i < 8; ++i) {
        int r = bm + ((i < 4) ? (ty * 4 + i) : (64 + ty * 4 + i - 4));
        if (r < M) {
            float* crow = C + (size_t)r * 256 + coff;
            *(float4*)(crow + tx * 4)      = make_float4(acc[i][0], acc[i][1], acc[i][2], acc[i][3]);
            *(float4*)(crow + 64 + tx * 4) = make_float4(acc[i][4], acc[i][5], acc[i][6], acc[i][7]);
        }
    }
}

// ---------------------------------------------------------------------------
// Small fp32 GEMM for layer 10 (A stride 128, nc<=64)
// ---------------------------------------------------------------------------
__global__ __launch_bounds__(256) void gemm_tile(const float* __restrict__ A,
                                                 const float* __restrict__ B,
                                                 float* __restrict__ C,
                                                 int M, int nc, int ldb, int ldc, int coff) {
    __shared__ float As[128][64];
    __shared__ float Bs[128][64];
    int t  = threadIdx.x;
    int bm = blockIdx.x * 64;
    int bn = blockIdx.y * 64;
    {
        int k4 = (t & 31) << 2;
        int r0 = t >> 5;
#pragma unroll
        for (int pass = 0; pass < 8; ++pass) {
            int row = r0 + pass * 8;
            int gm  = bm + row;
            float4 v = make_float4(0.f, 0.f, 0.f, 0.f);
            if (gm < M) v = *(const float4*)(A + (size_t)gm * 128 + k4);
            As[k4 + 0][row] = v.x; As[k4 + 1][row] = v.y;
            As[k4 + 2][row] = v.z; As[k4 + 3][row] = v.w;
        }
    }
    {
        int c4 = (t & 15) << 2;
        int kr = t >> 4;
#pragma unroll
        for (int pass = 0; pass < 8; ++pass) {
            int k  = kr + pass * 16;
            int gc = bn + c4;
            float4 v = make_float4(0.f, 0.f, 0.f, 0.f);
            if (gc < nc) v = *(const float4*)(B + (size_t)k * ldb + gc);
            *(float4*)&Bs[k][c4] = v;
        }
    }
    __syncthreads();

    int tx = t & 15, ty = t >> 4;
    int m0 = ty * 4, c0 = tx * 4;
    float acc[4][4] = {{0.f}};
#pragma unroll 8
    for (int k = 0; k < 128; ++k) {
        float4 av = *(const float4*)&As[k][m0];
        float4 bv = *(const float4*)&Bs[k][c0];
        float a4[4] = {av.x, av.y, av.z, av.w};
        float b4[4] = {bv.x, bv.y, bv.z, bv.w};
#pragma unroll
        for (int i = 0; i < 4; ++i)
#pragma unroll
            for (int j = 0; j < 4; ++j) acc[i][j] = fmaf(a4[i], b4[j], acc[i][j]);
    }
#pragma unroll
    for (int i = 0; i < 4; ++i) {
        int gm = bm + m0 + i;
        int gc = bn + c0;
        if (gm < M && gc < nc) {
            *(float4*)(C + (size_t)gm * ldc + coff + gc) =
                make_float4(acc[i][0], acc[i][1], acc[i][2], acc[i][3]);
        }
    }
}

// ---------------------------------------------------------------------------
// Node kernel layers 1-9: one wave/node, 4 independent online-softmax states,
// unroll-4 edge loop, packed (src,ea) stream.
// ---------------------------------------------------------------------------
__global__ __launch_bounds__(256) void node_agg_128(const float* __restrict__ xlr,
                                                    const int* __restrict__ row_start,
                                                    const int2* __restrict__ epack,
                                                    const float* __restrict__ We,
                                                    const float* __restrict__ att,
                                                    const float* __restrict__ bias,
                                                    const float* __restrict__ bng,
                                                    const float* __restrict__ bnb,
                                                    const float* __restrict__ bnm,
                                                    const float* __restrict__ bnv,
                                                    float* __restrict__ hout) {
    int wave = (blockIdx.x * blockDim.x + threadIdx.x) >> 6;
    int lane = threadIdx.x & 63;
    if (wave >= NN) return;
    int hh = lane >> 4, q = lane & 15;
    int f0 = hh * 32 + q;

    const float L2E = 1.44269504f;
    const float* xrrow = xlr + (size_t)wave * 256 + 128;
    float xr0 = xrrow[f0], xr1 = xrrow[f0 + 16];
    float we0 = We[f0],    we1 = We[f0 + 16];
    float at0 = att[f0],   at1 = att[f0 + 16];
    float a6_0 = 0.6f * L2E * at0, a4_0 = 0.4f * L2E * at0;
    float a6_1 = 0.6f * L2E * at1, a4_1 = 0.4f * L2E * at1;

    int beg = row_start[wave], end = row_start[wave + 1];

    float mxs[4] = {-INFINITY, -INFINITY, -INFINITY, -INFINITY};
    float sms[4] = {0.f, 0.f, 0.f, 0.f};
    float a0s[4] = {0.f, 0.f, 0.f, 0.f};
    float a1s[4] = {0.f, 0.f, 0.f, 0.f};

    auto upd = [&](int st, float xl0, float xl1, float eav) {
        float m0 = xl0 + fmaf(eav, we0, xr0);
        float m1 = xl1 + fmaf(eav, we1, xr1);
        float p = fmaf(a6_0, m0, fmaf(a4_0, fabsf(m0),
                  fmaf(a6_1, m1, a4_1 * fabsf(m1))));
        p += __shfl_xor(p, 8); p += __shfl_xor(p, 4);
        p += __shfl_xor(p, 2); p += __shfl_xor(p, 1);
        float nm = fmaxf(mxs[st], p);
        float sc = exp2f(mxs[st] - nm);
        float w  = exp2f(p - nm);
        sms[st] = fmaf(sms[st], sc, w);
        a0s[st] = fmaf(a0s[st], sc, w * xl0);
        a1s[st] = fmaf(a1s[st], sc, w * xl1);
        mxs[st] = nm;
    };

    int j = beg;
    for (; j + 3 < end; j += 4) {
        int2 p0 = epack[j],     p1 = epack[j + 1];
        int2 p2 = epack[j + 2], p3 = epack[j + 3];
        const float* r0 = xlr + ((size_t)p0.x << 8);
        const float* r1 = xlr + ((size_t)p1.x << 8);
        const float* r2 = xlr + ((size_t)p2.x << 8);
        const float* r3 = xlr + ((size_t)p3.x << 8);
        float x00 = r0[f0], x01 = r0[f0 + 16];
        float x10 = r1[f0], x11 = r1[f0 + 16];
        float x20 = r2[f0], x21 = r2[f0 + 16];
        float x30 = r3[f0], x31 = r3[f0 + 16];
        upd(0, x00, x01, __int_as_float(p0.y));
        upd(1, x10, x11, __int_as_float(p1.y));
        upd(2, x20, x21, __int_as_float(p2.y));
        upd(3, x30, x31, __int_as_float(p3.y));
    }
    for (int st = 0; j < end; ++j, ++st) {
        int2 pk = epack[j];
        const float* r0 = xlr + ((size_t)pk.x << 8);
        upd(st, r0[f0], r0[f0 + 16], __int_as_float(pk.y));
    }

    // merge states
    float M = fmaxf(fmaxf(mxs[0], mxs[1]), fmaxf(mxs[2], mxs[3]));
    float sm = 0.f, ac0 = 0.f, ac1 = 0.f;
#pragma unroll
    for (int st = 0; st < 4; ++st) {
        float sc = (mxs[st] == -INFINITY) ? 0.f : exp2f(mxs[st] - M);
        sm  = fmaf(sms[st], sc, sm);
        ac0 = fmaf(a0s[st], sc, ac0);
        ac1 = fmaf(a1s[st], sc, ac1);
    }

    float inv = 1.f / (sm + 1e-16f);
    float y0 = fmaf(ac0, inv, bias[f0]);
    float y1 = fmaf(ac1, inv, bias[f0 + 16]);
    y0 = fmaxf(y0, 0.f);
    y1 = fmaxf(y1, 0.f);
    y0 = (y0 - bnm[f0])      * rsqrtf(bnv[f0] + EPS)      * bng[f0]      + bnb[f0];
    y1 = (y1 - bnm[f0 + 16]) * rsqrtf(bnv[f0 + 16] + EPS) * bng[f0 + 16] + bnb[f0 + 16];
    hout[(size_t)wave * 128 + f0]      = y0;
    hout[(size_t)wave * 128 + f0 + 16] = y1;
}

// ---------------------------------------------------------------------------
// Layer 10: half-wave per node. H=1, C=32, xlr10: [N][64]. 2 states, unroll-2.
// ---------------------------------------------------------------------------
__global__ __launch_bounds__(256) void node_agg_l10(const float* __restrict__ xlr,
                                                    const int* __restrict__ row_start,
                                                    const int2* __restrict__ epack,
                                                    const float* __restrict__ We,
                                                    const float* __restrict__ att,
                                                    const float* __restrict__ bias,
                                                    const float* __restrict__ bng,
                                                    const float* __restrict__ bnb,
                                                    const float* __restrict__ bnm,
                                                    const float* __restrict__ bnv,
                                                    const float* __restrict__ linW,
                                                    const float* __restrict__ linb,
                                                    float* __restrict__ out) {
    int n = (blockIdx.x * blockDim.x + threadIdx.x) >> 5;
    int c = threadIdx.x & 31;
    if (n >= NN) return;

    const float L2E = 1.44269504f;
    float xr = xlr[(size_t)n * 64 + 32 + c];
    float we = We[c];
    float a6 = 0.6f * L2E * att[c], a4 = 0.4f * L2E * att[c];
    int beg = row_start[n], end = row_start[n + 1];

    float mxs[2] = {-INFINITY, -INFINITY};
    float sms[2] = {0.f, 0.f};
    float acs[2] = {0.f, 0.f};

    auto upd = [&](int st, float xl, float eav) {
        float m = xl + fmaf(eav, we, xr);
        float p = fmaf(a6, m, a4 * fabsf(m));
#pragma unroll
        for (int off = 16; off; off >>= 1) p += __shfl_xor(p, off);
        float nm = fmaxf(mxs[st], p);
        float sc = exp2f(mxs[st] - nm);
        float w  = exp2f(p - nm);
        sms[st] = fmaf(sms[st], sc, w);
        acs[st] = fmaf(acs[st], sc, w * xl);
        mxs[st] = nm;
    };

    int j = beg;
    for (; j + 1 < end; j += 2) {
        int2 p0 = epack[j], p1 = epack[j + 1];
        float x0 = xlr[((size_t)p0.x << 6) + c];
        float x1 = xlr[((size_t)p1.x << 6) + c];
        upd(0, x0, __int_as_float(p0.y));
        upd(1, x1, __int_as_float(p1.y));
    }
    if (j < end) {
        int2 pk = epack[j];
        upd(0, xlr[((size_t)pk.x << 6) + c], __int_as_float(pk.y));
    }

    float M = fmaxf(mxs[0], mxs[1]);
    float sm = 0.f, acc = 0.f;
#pragma unroll
    for (int st = 0; st < 2; ++st) {
        float sc = (mxs[st] == -INFINITY) ? 0.f : exp2f(mxs[st] - M);
        sm  = fmaf(sms[st], sc, sm);
        acc = fmaf(acs[st], sc, acc);
    }

    float y = acc / (sm + 1e-16f) + bias[c];
    y = fmaxf(y, 0.f);
    y = (y - bnm[c]) * rsqrtf(bnv[c] + EPS) * bng[c] + bnb[c];

    float t0 = y * linW[c * 4 + 0];
    float t1 = y * linW[c * 4 + 1];
    float t2 = y * linW[c * 4 + 2];
    float t3 = y * linW[c * 4 + 3];
#pragma unroll
    for (int off = 16; off; off >>= 1) {
        t0 += __shfl_xor(t0, off);
        t1 += __shfl_xor(t1, off);
        t2 += __shfl_xor(t2, off);
        t3 += __shfl_xor(t3, off);
    }
    if (c == 0) {
        out[(size_t)n * 4 + 0] = t0 + linb[0];
        out[(size_t)n * 4 + 1] = t1 + linb[1];
        out[(size_t)n * 4 + 2] = t2 + linb[2];
        out[(size_t)n * 4 + 3] = t3 + linb[3];
    }
}

// ---------------------------------------------------------------------------
extern "C" void kernel_launch(void* const* d_in, const int* in_sizes, int n_in,
                              void* d_out, int out_size, void* d_ws, size_t ws_size,
                              hipStream_t stream) {
    const float* x      = (const float*)d_in[0];
    const int*   ei     = (const int*)d_in[1];
    const float* ea     = (const float*)d_in[2];
    const float* l1_Wl  = (const float*)d_in[3];
    const float* l1_Wr  = (const float*)d_in[4];
    const float* l1_We  = (const float*)d_in[5];
    const float* l1_att = (const float*)d_in[6];
    const float* l1_b   = (const float*)d_in[7];
    const float* mid_Wl = (const float*)d_in[8];
    const float* mid_Wr = (const float*)d_in[9];
    const float* mid_We = (const float*)d_in[10];
    const float* mid_att= (const float*)d_in[11];
    const float* mid_b  = (const float*)d_in[12];
    const float* l10_Wl = (const float*)d_in[13];
    const float* l10_Wr = (const float*)d_in[14];
    const float* l10_We = (const float*)d_in[15];
    const float* l10_att= (const float*)d_in[16];
    const float* l10_b  = (const float*)d_in[17];
    const float* bn_g   = (const float*)d_in[18];
    const float* bn_b   = (const float*)d_in[19];
    const float* bn_m   = (const float*)d_in[20];
    const float* bn_v   = (const float*)d_in[21];
    const float* bn10_g = (const float*)d_in[22];
    const float* bn10_b = (const float*)d_in[23];
    const float* bn10_m = (const float*)d_in[24];
    const float* bn10_v = (const float*)d_in[25];
    const float* lin_W  = (const float*)d_in[26];
    const float* lin_b  = (const float*)d_in[27];

    char* ws = (char*)d_ws;
    auto take = [&](size_t bytes) { char* p = ws; ws += (bytes + 255) & ~size_t(255); return p; };
    int*   row_start  = (int*)  take(sizeof(int) * (NN + 1));
    int*   cursor     = (int*)  take(sizeof(int) * NN);
    int*   part       = (int*)  take(sizeof(int) * 256);
    int2*  epack      = (int2*) take(sizeof(int2) * EE);
    float* xlr        = (float*)take(sizeof(float) * (size_t)NN * 256);
    float* h0         = (float*)take(sizeof(float) * (size_t)NN * 128);
    float* h1         = (float*)take(sizeof(float) * (size_t)NN * 128);

    // --- CSR build ---
    hipMemsetAsync(cursor, 0, sizeof(int) * NN, stream);
    hist_kernel<<<EE / 256, 256, 0, stream>>>(ei + EE, cursor);
    scan_part<<<256, 256, 0, stream>>>(cursor, part);
    scan_block<<<1, 256, 0, stream>>>(part);
    scan_final<<<256, 256, 0, stream>>>(cursor, part, row_start);
    scatter_kernel<<<EE / 256, 256, 0, stream>>>(ei, ea, cursor, epack);

    const int GB = (NN + 127) / 128;  // 391
    dim3 gdual(GB, 2);

    // --- layer 1 ---
    gemm_dual<<<gdual, 256, 0, stream>>>(x, l1_Wl, l1_Wr, xlr, NN);
    node_agg_128<<<(NN * 64) / 256, 256, 0, stream>>>(
        xlr, row_start, epack, l1_We, l1_att, l1_b,
        bn_g, bn_b, bn_m, bn_v, h0);

    // --- layers 2-9 ---
    float* hin = h0;
    float* hout = h1;
    for (int i = 0; i < 8; ++i) {
        gemm_dual<<<gdual, 256, 0, stream>>>(hin, mid_Wl + (size_t)i * 128 * 128,
                                             mid_Wr + (size_t)i * 128 * 128, xlr, NN);
        node_agg_128<<<(NN * 64) / 256, 256, 0, stream>>>(
            xlr, row_start, epack,
            mid_We + (size_t)i * 128, mid_att + (size_t)i * 128, mid_b + (size_t)i * 128,
            bn_g + (size_t)(i + 1) * 128, bn_b + (size_t)(i + 1) * 128,
            bn_m + (size_t)(i + 1) * 128, bn_v + (size_t)(i + 1) * 128, hout);
        float* tmp = hin; hin = hout; hout = tmp;
    }

    // --- layer 10 (xlr reused as [N][64]) ---
    const int MB = (NN + 63) / 64;  // 782
    dim3 g1(MB, 1);
    gemm_tile<<<g1, 256, 0, stream>>>(hin, l10_Wl, xlr, NN, 32, 32, 64, 0);
    gemm_tile<<<g1, 256, 0, stream>>>(hin, l10_Wr, xlr, NN, 32, 32, 64, 32);
    node_agg_l10<<<(NN * 32 + 255) / 256, 256, 0, stream>>>(
        xlr, row_start, epack, l10_We, l10_att, l10_b,
        bn10_g, bn10_b, bn10_m, bn10_v, lin_W, lin_b, (float*)d_out);
}